// Round 1
// 263.727 us; speedup vs baseline: 1.1733x; 1.1733x over previous
//
#include <hip/hip_runtime.h>

// Problem: VQ-VAE codebook quantization
//   x: [32, 256, 32, 32] f32  -> z: [N=32768, D=256] (transposed view)
//   W: [1024, 256] f32 codebook (K=1024)
//   idx[n]   = argmin_k ( |z_n|^2 - 2 z_n.W_k + |W_k|^2 )   (first-min tie-break)
//   z_q.flat[n*256+d] = W[idx[n]][d]      (faithful "view" reshape bug)
//   loss = 1.25 * mean((z_q.flat - x.flat)^2)
// Outputs concatenated flat as f32: z_q (8388608), idx-as-float (32768), loss (1)
//
// R1: 8x8 register blocking (1 B LDS / FMA, was 2), async global_load_lds for z,
//     padded wT[32][260] + split code quads -> bank-floor LDS reads.

#define N_ROWS 32768
#define K_CODES 1024
#define D_DIM 256

#define ROWS 64   // rows per block
#define KT 256    // codes per k-tile (4 tiles cover K=1024)
#define DT 32     // dims per staged chunk
#define KTP 260   // padded wT row stride (words); 260%32=4 -> 4-way write scatter, aligned b128 reads

// ---------------- wsq + loss-accumulator zero ----------------
__global__ void wsq_kernel(const float* __restrict__ W, float* __restrict__ wsq,
                           float* __restrict__ loss_acc) {
    int k = blockIdx.x * blockDim.x + threadIdx.x;
    if (k == 0) *loss_acc = 0.0f;
    if (k < K_CODES) {
        const float4* w4 = (const float4*)(W + (size_t)k * D_DIM);
        float s = 0.0f;
#pragma unroll 8
        for (int i = 0; i < D_DIM / 4; i++) {
            float4 v = w4[i];
            s += v.x * v.x + v.y * v.y + v.z * v.z + v.w * v.w;
        }
        wsq[k] = s;
    }
}

// ---------------- fused distance-GEMM + argmin ----------------
// 256 threads: tr = t>>5 (8 row-groups of 8 rows), tc = t&31 (32 code-groups of 8 codes).
// Per thread: acc[8][8]; per d: 2 broadcast zr reads + 2 bank-floor wc reads -> 64 FMA.
__launch_bounds__(256, 3)
__global__ void argmin_kernel(const float* __restrict__ x, const float* __restrict__ W,
                              const float* __restrict__ wsq,
                              float* __restrict__ out_idx_f, int* __restrict__ ws_idx) {
    __shared__ float zT[DT][ROWS];   // 8 KB   zT[dloc][r] = z[n0+r][d0+dloc]
    __shared__ float wT[DT][KTP];    // 33.3 KB wT[dloc][k] = W[k0+k][d0+dloc]

    const int t    = threadIdx.x;
    const int lane = t & 63;
    const int wv   = t >> 6;      // wave id 0..3
    const int tc   = t & 31;
    const int tr   = t >> 5;
    const int tr8  = tr * 8;
    const int tc4  = tc * 4;

    const int n0  = blockIdx.x * ROWS;
    const int b   = n0 >> 10;         // 1024 rows per batch image (64 | 1024, no straddle)
    const int hw0 = n0 & 1023;
    const size_t xbase = (size_t)b * D_DIM * 1024;

    float rmin[8];
    int   ridx[8];
#pragma unroll
    for (int i = 0; i < 8; i++) { rmin[i] = 1e30f; ridx[i] = 0; }

#pragma unroll 1
    for (int k0 = 0; k0 < K_CODES; k0 += KT) {
        float acc[8][8] = {{0.f}};

        // per-thread codes this tile: k0 + g*128 + tc*4 + j (ascending in (g,j))
        float wsqv[8];
#pragma unroll
        for (int g = 0; g < 2; g++)
#pragma unroll
            for (int j = 0; j < 4; j++)
                wsqv[g * 4 + j] = wsq[k0 + g * 128 + tc4 + j];

#pragma unroll 1
        for (int d0 = 0; d0 < D_DIM; d0 += DT) {
            // ---- async stage z chunk: one width-16 gll writes 4 zT rows (wave-partitioned)
#pragma unroll
            for (int i = 0; i < 2; i++) {
                int dl0 = wv * 8 + i * 4;
                const float* src = x + xbase + ((size_t)(d0 + dl0 + (lane >> 4)) << 10)
                                 + hw0 + ((lane & 15) << 2);
                __builtin_amdgcn_global_load_lds(
                    (const __attribute__((address_space(1))) void*)src,
                    (__attribute__((address_space(3))) void*)&zT[dl0][0],
                    16, 0, 0);
            }
            // ---- reg-stage W transpose chunk: coalesced float4 reads, 4-way scatter writes
#pragma unroll
            for (int i = 0; i < 8; i++) {
                int e  = t + i * 256;          // 0..2047
                int kk = e >> 3;               // 0..255
                int dg = e & 7;                // 0..7
                float4 v = *(const float4*)(W + (size_t)(k0 + kk) * D_DIM + d0 + dg * 4);
                wT[dg * 4 + 0][kk] = v.x;
                wT[dg * 4 + 1][kk] = v.y;
                wT[dg * 4 + 2][kk] = v.z;
                wT[dg * 4 + 3][kk] = v.w;
            }
            __syncthreads();   // drains vmcnt (gll) + lds writes

#pragma unroll 8
            for (int d = 0; d < DT; d++) {
                float zr[8], wc[8];
                *(float4*)&zr[0] = *(const float4*)&zT[d][tr8];       // broadcast (2 addrs/wave)
                *(float4*)&zr[4] = *(const float4*)&zT[d][tr8 + 4];
                *(float4*)&wc[0] = *(const float4*)&wT[d][tc4];       // 512B unique = bank floor
                *(float4*)&wc[4] = *(const float4*)&wT[d][tc4 + 128];
#pragma unroll
                for (int i = 0; i < 8; i++)
#pragma unroll
                    for (int j = 0; j < 8; j++)
                        acc[i][j] = fmaf(zr[i], wc[j], acc[i][j]);
            }
            __syncthreads();
        }

        // ---- score & update running argmin (k ascending within thread => strict <)
#pragma unroll
        for (int g = 0; g < 2; g++)
#pragma unroll
            for (int j = 0; j < 4; j++) {
                int k = k0 + g * 128 + tc4 + j;
                float ws = wsqv[g * 4 + j];
#pragma unroll
                for (int i = 0; i < 8; i++) {
                    float s = ws - 2.0f * acc[i][g * 4 + j];
                    if (s < rmin[i]) { rmin[i] = s; ridx[i] = k; }
                }
            }
    }

    // ---- reduce across the 32 tc lanes (same half-wave; off<=16 stays in half)
#pragma unroll
    for (int off = 1; off < 32; off <<= 1) {
#pragma unroll
        for (int i = 0; i < 8; i++) {
            float ov = __shfl_xor(rmin[i], off);
            int   oi = __shfl_xor(ridx[i], off);
            if (ov < rmin[i] || (ov == rmin[i] && oi < ridx[i])) { rmin[i] = ov; ridx[i] = oi; }
        }
    }
    if (tc == 0) {
#pragma unroll
        for (int i = 0; i < 8; i++) {
            int n = n0 + tr8 + i;
            ws_idx[n]    = ridx[i];
            out_idx_f[n] = (float)ridx[i];
        }
    }
}

// ---------------- gather z_q + loss SSE ----------------
__global__ void gather_loss_kernel(const float* __restrict__ x, const float* __restrict__ W,
                                   const int* __restrict__ ws_idx,
                                   float* __restrict__ out_zq, float* __restrict__ loss_acc) {
    __shared__ float red[256];
    const size_t P4 = (size_t)N_ROWS * D_DIM / 4;   // 2097152 float4s
    size_t tid = (size_t)blockIdx.x * blockDim.x + threadIdx.x;
    size_t stride = (size_t)gridDim.x * blockDim.x;
    float acc = 0.0f;
    for (size_t p4 = tid; p4 < P4; p4 += stride) {
        int n = (int)(p4 >> 6);            // 64 float4s per row
        int j = (int)((p4 & 63) << 2);
        int k = ws_idx[n];
        float4 wv = *(const float4*)(W + (size_t)k * D_DIM + j);
        float4 xv = *(const float4*)(x + p4 * 4);
        float dx = wv.x - xv.x, dy = wv.y - xv.y, dz = wv.z - xv.z, dw = wv.w - xv.w;
        acc += dx * dx + dy * dy + dz * dz + dw * dw;
        *(float4*)(out_zq + p4 * 4) = wv;
    }
    red[threadIdx.x] = acc;
    __syncthreads();
    for (int s = 128; s > 0; s >>= 1) {
        if ((int)threadIdx.x < s) red[threadIdx.x] += red[threadIdx.x + s];
        __syncthreads();
    }
    if (threadIdx.x == 0) atomicAdd(loss_acc, red[0]);
}

__global__ void finalize_kernel(const float* __restrict__ loss_acc, float* __restrict__ out_loss) {
    out_loss[0] = 1.25f * loss_acc[0] * (1.0f / 8388608.0f);
}

extern "C" void kernel_launch(void* const* d_in, const int* in_sizes, int n_in,
                              void* d_out, int out_size, void* d_ws, size_t ws_size,
                              hipStream_t stream) {
    const float* x = (const float*)d_in[0];   // 32*256*32*32
    const float* W = (const float*)d_in[1];   // 1024*256

    float* out      = (float*)d_out;
    float* out_zq   = out;                         // 8388608
    float* out_idx  = out + 8388608;               // 32768
    float* out_loss = out + 8388608 + 32768;       // 1

    float* loss_acc = (float*)d_ws;                          // 4 B
    float* wsq      = (float*)((char*)d_ws + 4096);          // 4 KB
    int*   ws_idx   = (int*)((char*)d_ws + 8192);            // 128 KB

    wsq_kernel<<<4, 256, 0, stream>>>(W, wsq, loss_acc);
    argmin_kernel<<<N_ROWS / ROWS, 256, 0, stream>>>(x, W, wsq, out_idx, ws_idx);
    gather_loss_kernel<<<2048, 256, 0, stream>>>(x, W, ws_idx, out_zq, loss_acc);
    finalize_kernel<<<1, 1, 0, stream>>>(loss_acc, out_loss);
}